// Round 1
// baseline (5205.140 us; speedup 1.0000x reference)
//
#include <hip/hip_runtime.h>

// 4-layer bidirectional LSTM, B=128, T=4096, H=13 (gates 4H=52).
// One wave per (batch, direction); lane g owns gate g. Latency-bound design.

constexpr int LANES = 64;
constexpr int Hh    = 13;     // hidden
constexpr int G4    = 52;     // 4*H gates
constexpr int T_LEN = 4096;
constexpr int BATCH = 128;
constexpr int CH    = 64;     // timestep chunk staged in LDS
constexpr int RS    = 28;     // padded LDS row stride (16B aligned)

__device__ __forceinline__ float fast_rcp(float x) {
    return __builtin_amdgcn_rcpf(x);
}

template<int K>
__global__ __launch_bounds__(64, 1)
void lstm_dir_kernel(const float* __restrict__ act,   // [B][T][K]
                     const float* __restrict__ wih,   // [2][52][K]
                     const float* __restrict__ whh,   // [2][52][13]
                     const float* __restrict__ bih,   // [2][52]
                     const float* __restrict__ bhh,   // [2][52]
                     float* __restrict__ out)         // [B][T][26]; dir d -> cols [d*13, d*13+13)
{
    constexpr int NCH = T_LEN / CH;
    constexpr int SN  = CH * K / LANES;   // staged floats per lane per chunk (13 or 26)

    const int lane = threadIdx.x;
    const int d    = blockIdx.x & 1;
    const int b    = blockIdx.x >> 1;
    const int g    = (lane < G4) ? lane : (G4 - 1);
    const int j    = lane % Hh;
    const bool isg = (lane >= 2 * Hh) && (lane < 3 * Hh);   // tanh gate rows 26..38

    __shared__ __align__(16) float xl[2][CH][RS];

    // per-lane weights
    float wi[K];
    {
        const float* p = wih + (size_t)(d * G4 + g) * K;
        #pragma unroll
        for (int k = 0; k < K; ++k) wi[k] = p[k];
    }
    float wh[Hh];
    {
        const float* p = whh + (size_t)(d * G4 + g) * Hh;
        #pragma unroll
        for (int k = 0; k < Hh; ++k) wh[k] = p[k];
    }
    const float p0 = bih[d * G4 + g] + bhh[d * G4 + g];

    const float* actb = act + (size_t)b * T_LEN * K;
    auto chunk_ptr = [&](int c) -> const float* {
        int st = (d == 0) ? (c * CH) : (T_LEN - (c + 1) * CH);
        return actb + (size_t)st * K;
    };

    // stage chunk 0 into LDS buf0; prefetch chunk 1 into regs
    float stg[SN];
    {
        const float* p = chunk_ptr(0);
        #pragma unroll
        for (int m = 0; m < SN; ++m) stg[m] = p[m * LANES + lane];
        #pragma unroll
        for (int m = 0; m < SN; ++m) {
            int idx = m * LANES + lane;
            xl[0][idx / K][idx % K] = stg[m];
        }
        const float* p1 = chunk_ptr(1);
        #pragma unroll
        for (int m = 0; m < SN; ++m) stg[m] = p1[m * LANES + lane];
    }

    float hreg = 0.0f, cst = 0.0f;

    for (int c = 0; c < NCH; ++c) {
        const float (*xb)[RS] = xl[c & 1];

        #pragma unroll 2
        for (int s = 0; s < CH; ++s) {
            const int row = (d == 0) ? s : (CH - 1 - s);
            const float* xr = xb[row];

            // 4-way split accumulators to shorten FMA chains
            float accv[4] = {p0, 0.0f, 0.0f, 0.0f};

            // recurrent dot: h broadcast via shuffles (issue early)
            #pragma unroll
            for (int k = 0; k < Hh; ++k) {
                float hk = __shfl(hreg, k);
                accv[k & 3] = fmaf(hk, wh[k], accv[k & 3]);
            }

            // input dot from LDS chunk (vectorized reads)
            constexpr int NV4 = K / 4;
            const float4* xr4 = reinterpret_cast<const float4*>(xr);
            float4 vv[NV4];
            #pragma unroll
            for (int q = 0; q < NV4; ++q) vv[q] = xr4[q];
            #pragma unroll
            for (int q = 0; q < NV4; ++q) {
                accv[0] = fmaf(vv[q].x, wi[4 * q + 0], accv[0]);
                accv[1] = fmaf(vv[q].y, wi[4 * q + 1], accv[1]);
                accv[2] = fmaf(vv[q].z, wi[4 * q + 2], accv[2]);
                accv[3] = fmaf(vv[q].w, wi[4 * q + 3], accv[3]);
            }
            #pragma unroll
            for (int k = NV4 * 4; k < K; ++k)
                accv[k & 3] = fmaf(xr[k], wi[k], accv[k & 3]);

            float acc = (accv[0] + accv[1]) + (accv[2] + accv[3]);

            // activation: sigmoid, or tanh = 2*sigmoid(2x)-1 for gate rows
            float xx = isg ? (2.0f * acc) : acc;
            float u  = __expf(-xx);
            float sgm = fast_rcp(1.0f + u);
            float a  = isg ? fmaf(2.0f, sgm, -1.0f) : sgm;

            // gather the 4 gates of unit j
            float iv = __shfl(a, j);
            float fv = __shfl(a, j + Hh);
            float gv = __shfl(a, j + 2 * Hh);
            float ov = __shfl(a, j + 3 * Hh);

            cst = fmaf(fv, cst, iv * gv);
            // tanh(c)
            float u2 = __expf(-2.0f * cst);
            float tc = fmaf(2.0f, fast_rcp(1.0f + u2), -1.0f);
            hreg = ov * tc;

            const int tt = (d == 0) ? (c * CH + s) : (T_LEN - 1 - (c * CH + s));
            if (lane < Hh)
                out[((size_t)b * T_LEN + tt) * 26 + d * Hh + lane] = hreg;
        }

        // write prefetched chunk to the other LDS buffer; prefetch next
        if (c + 1 < NCH) {
            #pragma unroll
            for (int m = 0; m < SN; ++m) {
                int idx = m * LANES + lane;
                xl[(c + 1) & 1][idx / K][idx % K] = stg[m];
            }
            if (c + 2 < NCH) {
                const float* p = chunk_ptr(c + 2);
                #pragma unroll
                for (int m = 0; m < SN; ++m) stg[m] = p[m * LANES + lane];
            }
        }
    }
}

extern "C" void kernel_launch(void* const* d_in, const int* in_sizes, int n_in,
                              void* d_out, int out_size, void* d_ws, size_t ws_size,
                              hipStream_t stream) {
    const float* x     = (const float*)d_in[0];
    const float* w_ih0 = (const float*)d_in[1];
    const float* w_hh0 = (const float*)d_in[2];
    const float* b_ih0 = (const float*)d_in[3];
    const float* b_hh0 = (const float*)d_in[4];
    const float* w_ihr = (const float*)d_in[5];   // [3][2][52][26]
    const float* w_hhr = (const float*)d_in[6];   // [3][2][52][13]
    const float* b_ihr = (const float*)d_in[7];   // [3][2][52]
    const float* b_hhr = (const float*)d_in[8];   // [3][2][52]

    float* out = (float*)d_out;                   // [B][T][26]
    float* buf = (float*)d_ws;                    // [B][T][26] ping buffer (54.5 MB)

    dim3 grid(BATCH * 2), block(LANES);

    // layer 0: x (K=13) -> buf
    lstm_dir_kernel<13><<<grid, block, 0, stream>>>(x, w_ih0, w_hh0, b_ih0, b_hh0, buf);
    // layer 1: buf -> out
    lstm_dir_kernel<26><<<grid, block, 0, stream>>>(
        buf, w_ihr + 0 * 2 * G4 * 26, w_hhr + 0 * 2 * G4 * Hh,
        b_ihr + 0 * 2 * G4, b_hhr + 0 * 2 * G4, out);
    // layer 2: out -> buf
    lstm_dir_kernel<26><<<grid, block, 0, stream>>>(
        out, w_ihr + 1 * 2 * G4 * 26, w_hhr + 1 * 2 * G4 * Hh,
        b_ihr + 1 * 2 * G4, b_hhr + 1 * 2 * G4, buf);
    // layer 3: buf -> out
    lstm_dir_kernel<26><<<grid, block, 0, stream>>>(
        buf, w_ihr + 2 * 2 * G4 * 26, w_hhr + 2 * 2 * G4 * Hh,
        b_ihr + 2 * 2 * G4, b_hhr + 2 * 2 * G4, out);
}

// Round 4
// 3098.179 us; speedup vs baseline: 1.6801x; 1.6801x over previous
//
#include <hip/hip_runtime.h>

// 4-layer bidirectional LSTM, B=128, T=4096, H=13 (gates 4H=52).
// One wave per (batch, direction). Quad layout: lane l -> unit j=l>>2, gate q=l&3
// (q: 0=i,1=f,2=g,3=o). Cross-lane via readlane (const lane -> SGPR) and DPP
// quad broadcasts only -- zero LDS-pipe ops in the recurrent chain except the
// same-address (broadcast, conflict-free) x-tile reads.

constexpr int T_LEN = 4096;
constexpr int BATCH = 128;
constexpr int CH    = 64;                      // timesteps per LDS chunk
constexpr float LOG2E = 1.4426950408889634f;

__device__ __forceinline__ float rl_f(float v, int lane) {
    return __int_as_float(__builtin_amdgcn_readlane(__float_as_int(v), lane));
}
template<int PAT>
__device__ __forceinline__ float qb(float v) {
    // quad_perm broadcast: PAT 0x00->lane0, 0x55->lane1, 0xAA->lane2, 0xFF->lane3
    return __int_as_float(__builtin_amdgcn_update_dpp(0, __float_as_int(v), PAT, 0xf, 0xf, true));
}

template<int K>
__global__ __launch_bounds__(64, 1)
void lstm_seq(const float* __restrict__ act,   // [B][T][K]
              const float* __restrict__ wih,   // [2][52][K]
              const float* __restrict__ whh,   // [2][52][13]
              const float* __restrict__ bih,   // [2][52]
              const float* __restrict__ bhh,   // [2][52]
              float* __restrict__ out)         // [B][T][26]
{
    constexpr int RSF = (K == 13) ? 16 : 28;   // padded LDS row floats (16B aligned)
    constexpr int NCH = T_LEN / CH;

    const int lane = threadIdx.x;
    const int d    = blockIdx.x & 1;
    const int b    = blockIdx.x >> 1;
    const int q    = lane & 3;                 // gate index
    const int jj   = lane >> 2;                // unit index (garbage for jj>=13)
    const int j    = (jj < 13) ? jj : 12;
    const int r    = q * 13 + j;               // row in [4H]-major weights

    // pre-scale so exp2(acc) == exp(-x) (sigmoid) or exp(-2x) (tanh gate q==2)
    const float sq    = (q == 2) ? (-2.0f * LOG2E) : (-LOG2E);
    const float postA = (q == 2) ? 2.0f : 1.0f;
    const float postB = (q == 2) ? -1.0f : 0.0f;

    __shared__ __align__(16) float xl[2][CH][RSF];

    float wi[K], wh[13];
    {
        const float* p = wih + (size_t)(d * 52 + r) * K;
        #pragma unroll
        for (int k = 0; k < K; ++k) wi[k] = p[k] * sq;
    }
    {
        const float* p = whh + (size_t)(d * 52 + r) * 13;
        #pragma unroll
        for (int k = 0; k < 13; ++k) wh[k] = p[k] * sq;
    }
    const float p0 = (bih[d * 52 + r] + bhh[d * 52 + r]) * sq;

    const float* actb = act + (size_t)b * T_LEN * K;

    // lane l stages global row (gbase+l) of the chunk; bwd writes LDS reversed so
    // the step loop always walks LDS rows forward.
    float stag[K];
    auto load_chunk = [&](int c) {
        const int gbase = d ? (T_LEN - CH * (c + 1)) : (CH * c);
        const float* p  = actb + (size_t)(gbase + lane) * K;
        if constexpr (K == 26) {
            const float2* p2 = reinterpret_cast<const float2*>(p);  // rows 8B aligned
            #pragma unroll
            for (int i = 0; i < 13; ++i) { float2 v = p2[i]; stag[2*i] = v.x; stag[2*i+1] = v.y; }
        } else {
            #pragma unroll
            for (int i = 0; i < K; ++i) stag[i] = p[i];
        }
    };
    auto write_chunk = [&](int nb) {
        const int lrow = d ? (CH - 1 - lane) : lane;
        float* rowp = &xl[nb][lrow][0];
        #pragma unroll
        for (int i = 0; i + 4 <= K; i += 4)
            *reinterpret_cast<float4*>(rowp + i) = make_float4(stag[i], stag[i+1], stag[i+2], stag[i+3]);
        if constexpr (K == 26)
            *reinterpret_cast<float2*>(rowp + 24) = make_float2(stag[24], stag[25]);
        else
            rowp[12] = stag[12];
    };

    float a0, a1, a2, a3;                       // pipelined input-dot partials
    auto xdot = [&](const float* rowp) {
        float c0 = p0, c1 = 0.f, c2 = 0.f, c3 = 0.f;
        #pragma unroll
        for (int i = 0; i + 4 <= K; i += 4) {
            float4 v = *reinterpret_cast<const float4*>(rowp + i);   // same-addr broadcast
            c0 = fmaf(v.x, wi[i],     c0);
            c1 = fmaf(v.y, wi[i + 1], c1);
            c2 = fmaf(v.z, wi[i + 2], c2);
            c3 = fmaf(v.w, wi[i + 3], c3);
        }
        if constexpr (K == 26) {
            float2 v = *reinterpret_cast<const float2*>(rowp + 24);
            c0 = fmaf(v.x, wi[24], c0);
            c1 = fmaf(v.y, wi[25], c1);
        } else {
            c0 = fmaf(rowp[12], wi[12], c0);
        }
        a0 = c0; a1 = c1; a2 = c2; a3 = c3;
    };

    float hreg = 0.0f, cst = 0.0f;
    float* outp = out + ((size_t)b * T_LEN + (d ? T_LEN - 1 : 0)) * 26 + d * 13 + j;
    const int ostep   = d ? -26 : 26;
    const bool dostore = (q == 0) && (jj < 13);

    auto step = [&]() {
        float bb[4] = {a0, a1, a2, a3};
        // recurrent dot: h broadcast via constant-lane readlane -> SGPR fma operands
        #pragma unroll
        for (int k = 0; k < 13; ++k) {
            float hk = rl_f(hreg, 4 * k);
            bb[k & 3] = fmaf(hk, wh[k], bb[k & 3]);
        }
        float acc = (bb[0] + bb[1]) + (bb[2] + bb[3]);      // pre-scaled by sq
        float u   = __builtin_amdgcn_exp2f(acc);
        float sg  = __builtin_amdgcn_rcpf(1.0f + u);
        float a   = fmaf(postA, sg, postB);                 // sigmoid or tanh
        // gather the quad's 4 gates via DPP (VALU-rate)
        float iv = qb<0x00>(a);
        float fv = qb<0x55>(a);
        float gv = qb<0xAA>(a);
        float ov = qb<0xFF>(a);
        cst = fmaf(fv, cst, iv * gv);
        float u2 = __builtin_amdgcn_exp2f(cst * (-2.0f * LOG2E));
        float tc = fmaf(2.0f, __builtin_amdgcn_rcpf(1.0f + u2), -1.0f);
        hreg = ov * tc;
        if (dostore) *outp = hreg;
        outp += ostep;
    };

    // prologue: stage chunk 0, start loads for chunk 1, prime the xdot pipeline
    load_chunk(0);
    write_chunk(0);
    load_chunk(1);
    xdot(&xl[0][0][0]);

    for (int c = 0; c < NCH; ++c) {
        const float* xb = &xl[c & 1][0][0];
        #pragma unroll 8
        for (int s = 0; s < CH - 8; ++s) {      // 56 iters
            step();
            xdot(xb + (s + 1) * RSF);           // next step's input dot in the stall shadow
        }
        #pragma unroll
        for (int s = CH - 8; s < CH - 1; ++s) {
            step();
            xdot(xb + (s + 1) * RSF);
        }
        step();                                  // s = CH-1
        if (c + 1 < NCH) {
            write_chunk((c + 1) & 1);            // staged regs -> other LDS buffer
            if (c + 2 < NCH) load_chunk(c + 2);  // issue next global loads (64-step window)
            xdot(&xl[(c + 1) & 1][0][0]);        // re-prime pipeline for new chunk
        }
    }
}

extern "C" void kernel_launch(void* const* d_in, const int* in_sizes, int n_in,
                              void* d_out, int out_size, void* d_ws, size_t ws_size,
                              hipStream_t stream) {
    const float* x     = (const float*)d_in[0];
    const float* w_ih0 = (const float*)d_in[1];
    const float* w_hh0 = (const float*)d_in[2];
    const float* b_ih0 = (const float*)d_in[3];
    const float* b_hh0 = (const float*)d_in[4];
    const float* w_ihr = (const float*)d_in[5];   // [3][2][52][26]
    const float* w_hhr = (const float*)d_in[6];   // [3][2][52][13]
    const float* b_ihr = (const float*)d_in[7];   // [3][2][52]
    const float* b_hhr = (const float*)d_in[8];   // [3][2][52]

    float* out = (float*)d_out;                   // [B][T][26]
    float* buf = (float*)d_ws;                    // [B][T][26] ping buffer (54.5 MB)

    dim3 grid(BATCH * 2), block(64);

    lstm_seq<13><<<grid, block, 0, stream>>>(x, w_ih0, w_hh0, b_ih0, b_hh0, buf);
    lstm_seq<26><<<grid, block, 0, stream>>>(
        buf, w_ihr + 0 * 2 * 52 * 26, w_hhr + 0 * 2 * 52 * 13,
        b_ihr + 0 * 2 * 52, b_hhr + 0 * 2 * 52, out);
    lstm_seq<26><<<grid, block, 0, stream>>>(
        out, w_ihr + 1 * 2 * 52 * 26, w_hhr + 1 * 2 * 52 * 13,
        b_ihr + 1 * 2 * 52, b_hhr + 1 * 2 * 52, buf);
    lstm_seq<26><<<grid, block, 0, stream>>>(
        buf, w_ihr + 2 * 2 * 52 * 26, w_hhr + 2 * 2 * 52 * 13,
        b_ihr + 2 * 2 * 52, b_hhr + 2 * 2 * 52, out);
}